// Round 2
// baseline (219.363 us; speedup 1.0000x reference)
//
#include <hip/hip_runtime.h>

// BIATT: B=16, Lc=Lp=1024, D=128, H=4, PFEAT=1024. All inputs fp32.
// Algebra: cv is rank-1 (c[b,l]*cp[d]) => A = tanh(c[b,l]*g[b,h,m]);
// scores reduce to 1D sums over tanh of an outer product.
// Precision: split-bf16 (hi+lo) MFMA => ~fp32-equivalent GEMMs.

using bf16x8 = __attribute__((ext_vector_type(8))) short;
using u16x8  = __attribute__((ext_vector_type(8))) unsigned short;
using f32x4  = __attribute__((ext_vector_type(4))) float;

__device__ __forceinline__ float tanh_fast(float x){
  float e = __expf(2.0f * x);
  return 1.0f - __fdividef(2.0f, e + 1.0f);
}
__device__ __forceinline__ unsigned short f2bf(float f){
  unsigned u = __float_as_uint(f);
  u = (u + 0x7FFFu + ((u >> 16) & 1u)) >> 16; // RNE
  return (unsigned short)u;
}
__device__ __forceinline__ float bf2f(unsigned short s){
  return __uint_as_float((unsigned)s << 16);
}
// split x -> hi + lo (two bf16), packed as pairs for vector stores
__device__ __forceinline__ void split4(float4 v, uint2& hi, uint2& lo){
  unsigned short hx = f2bf(v.x), hy = f2bf(v.y), hz = f2bf(v.z), hw = f2bf(v.w);
  unsigned short lx = f2bf(v.x - bf2f(hx)), ly = f2bf(v.y - bf2f(hy));
  unsigned short lz = f2bf(v.z - bf2f(hz)), lw = f2bf(v.w - bf2f(hw));
  hi = make_uint2((unsigned)hx | ((unsigned)hy << 16), (unsigned)hz | ((unsigned)hw << 16));
  lo = make_uint2((unsigned)lx | ((unsigned)ly << 16), (unsigned)lz | ((unsigned)lw << 16));
}

// ---------------------------------------------------------------- K0: prep
__global__ __launch_bounds__(256) void k0_prep(
    const float* __restrict__ c, const float* __restrict__ c_mask,
    const float* __restrict__ c_param, const float* __restrict__ p_param,
    const float* __restrict__ U, const float* __restrict__ W_p2c,
    const float* __restrict__ W_c2p, const float* __restrict__ Wh_c,
    const float* __restrict__ Wh_p, const float* __restrict__ bh_c,
    const float* __restrict__ b_c2p, const float* __restrict__ Wa_c,
    const float* __restrict__ Wa_p, const float* __restrict__ W_comb_c,
    unsigned short* __restrict__ ppT_hi, unsigned short* __restrict__ ppT_lo,
    unsigned short* __restrict__ wp2cT_hi, unsigned short* __restrict__ wp2cT_lo,
    unsigned short* __restrict__ whpT_hi, unsigned short* __restrict__ whpT_lo,
    float* __restrict__ uh, float* __restrict__ wccv,
    float* __restrict__ hcw, float* __restrict__ ctw)
{
  int bid = blockIdx.x, t = threadIdx.x;
  if (bid < 4) {
    int h = bid;
    if (t < 128) {
      float s_uh = 0.f, s_wcc = 0.f;
      for (int d = 0; d < 128; ++d) {
        float cp = c_param[d];
        s_uh  += cp * U[(h*128 + d)*128 + t];
        s_wcc += cp * W_comb_c[(h*128 + d)*128 + t];
      }
      uh[h*128 + t]   = s_uh;
      wccv[h*128 + t] = s_wcc;
    }
  } else if (bid < 36) {
    int base = (bid - 4) * 8192;
    for (int j = 0; j < 32; ++j) {
      int idx = base + j*256 + t;
      float v; unsigned short* dh; unsigned short* dl; int o;
      if (idx < 131072) {                       // ppT[e][k] = p_param[k][e]
        int e = idx >> 10, k = idx & 1023;
        v = p_param[k*128 + e]; dh = ppT_hi; dl = ppT_lo; o = idx;
      } else if (idx < 196608) {                // wp2cT[h][e][k] = W_p2c[h][k][e]
        int i2 = idx - 131072;
        int k = i2 & 127, e = (i2 >> 7) & 127, h = i2 >> 14;
        v = W_p2c[(h*128 + k)*128 + e]; dh = wp2cT_hi; dl = wp2cT_lo; o = i2;
      } else {                                  // whpT[h][e][k] = Wh_p[h][k][e]
        int i2 = idx - 196608;
        int k = i2 & 127, e = (i2 >> 7) & 127, h = i2 >> 14;
        v = Wh_p[(h*128 + k)*128 + e]; dh = whpT_hi; dl = whpT_lo; o = i2;
      }
      unsigned short hh = f2bf(v);
      dh[o] = hh;
      dl[o] = f2bf(v - bf2f(hh));
    }
  } else {
    int i = bid - 36;
    int b = i >> 4, h = (i >> 2) & 3, lc = i & 3;
    __shared__ float whc_l[128], wc2p_l[128], bhc_l[128], bc2p_l[128], wac1_l[128], wap2_l[128];
    if (t < 128) {
      float s1 = 0.f, s2 = 0.f;
      for (int d = 0; d < 128; ++d) {
        float cp = c_param[d];
        s1 += cp * Wh_c[(h*128 + d)*128 + t];
        s2 += cp * W_c2p[(h*128 + d)*128 + t];
      }
      whc_l[t] = s1; wc2p_l[t] = s2;
      bhc_l[t]  = bh_c[h*128 + t];
      bc2p_l[t] = b_c2p[h*128 + t];
      wac1_l[t] = Wa_c[h*256 + t];
      wap2_l[t] = Wa_p[h*256 + 128 + t];
    }
    __syncthreads();
    int l = lc*256 + t;
    float cl = c[b*1024 + l];
    float a1 = 0.f, a2 = 0.f;
    for (int e = 0; e < 128; ++e) {
      a1 += wac1_l[e] * tanh_fast(cl*whc_l[e]  + bhc_l[e]);
      a2 += wap2_l[e] * tanh_fast(cl*wc2p_l[e] + bc2p_l[e]);
    }
    int o = (b*4 + h)*1024 + l;
    hcw[o] = a1;
    ctw[o] = c_mask[b*1024 + l] * a2;     // fold c_mask into ctw
  }
}

// ---------------------------------------------------------------- K1: pv = p @ p_param (split-bf16 MFMA)
__global__ __launch_bounds__(256) void k1_pv(
    const float* __restrict__ p,
    const unsigned short* __restrict__ ppT_hi, const unsigned short* __restrict__ ppT_lo,
    float* __restrict__ pv_f32)
{
  __shared__ __align__(16) short Ah[32*40], Al[32*40];   // [row][k], pitch 40
  __shared__ __align__(16) short Bh[128*40], Bl[128*40]; // [col][k], pitch 40
  int t = threadIdx.x;
  int row0 = blockIdx.x * 32;

  int arow = t >> 3, ak = (t & 7) * 4;
  int bcol = t >> 1, bk = (t & 1) * 16;
  const float* pA = p + (row0 + arow)*1024 + ak;
  const unsigned short* pBh = ppT_hi + bcol*1024 + bk;
  const unsigned short* pBl = ppT_lo + bcol*1024 + bk;

  float4 ra  = *(const float4*)(pA);
  u16x8  rbh0 = *(const u16x8*)(pBh), rbh1 = *(const u16x8*)(pBh + 8);
  u16x8  rbl0 = *(const u16x8*)(pBl), rbl1 = *(const u16x8*)(pBl + 8);

  f32x4 acc[4];
  #pragma unroll
  for (int n = 0; n < 4; ++n) acc[n] = (f32x4){0.f,0.f,0.f,0.f};

  int w = t >> 6, lane = t & 63;
  int l15 = lane & 15, kk = (lane >> 4) * 8;
  int rowblk = (w & 1) * 16, colblk = (w >> 1) * 64;
  int arow_l = rowblk + l15;

  for (int kt = 0; kt < 32; ++kt) {
    __syncthreads();
    {
      uint2 hi, lo; split4(ra, hi, lo);
      *(uint2*)&Ah[arow*40 + ak] = hi;
      *(uint2*)&Al[arow*40 + ak] = lo;
      *(u16x8*)&Bh[bcol*40 + bk]     = rbh0;
      *(u16x8*)&Bh[bcol*40 + bk + 8] = rbh1;
      *(u16x8*)&Bl[bcol*40 + bk]     = rbl0;
      *(u16x8*)&Bl[bcol*40 + bk + 8] = rbl1;
    }
    if (kt < 31) {
      ra   = *(const float4*)(pA + (kt+1)*32);
      rbh0 = *(const u16x8*)(pBh + (kt+1)*32);
      rbh1 = *(const u16x8*)(pBh + (kt+1)*32 + 8);
      rbl0 = *(const u16x8*)(pBl + (kt+1)*32);
      rbl1 = *(const u16x8*)(pBl + (kt+1)*32 + 8);
    }
    __syncthreads();
    bf16x8 afh = *(const bf16x8*)&Ah[arow_l*40 + kk];
    bf16x8 afl = *(const bf16x8*)&Al[arow_l*40 + kk];
    #pragma unroll
    for (int n = 0; n < 4; ++n) {
      bf16x8 bfh = *(const bf16x8*)&Bh[(colblk + n*16 + l15)*40 + kk];
      bf16x8 bfl = *(const bf16x8*)&Bl[(colblk + n*16 + l15)*40 + kk];
      acc[n] = __builtin_amdgcn_mfma_f32_16x16x32_bf16(afh, bfh, acc[n], 0, 0, 0);
      acc[n] = __builtin_amdgcn_mfma_f32_16x16x32_bf16(afh, bfl, acc[n], 0, 0, 0);
      acc[n] = __builtin_amdgcn_mfma_f32_16x16x32_bf16(afl, bfh, acc[n], 0, 0, 0);
    }
  }
  #pragma unroll
  for (int n = 0; n < 4; ++n) {
    int col = colblk + n*16 + l15;
    #pragma unroll
    for (int r = 0; r < 4; ++r) {
      int row = row0 + rowblk + (lane >> 4)*4 + r;
      pv_f32[row*128 + col] = acc[n][r];
    }
  }
}

// ---------------------------------------------------------------- K2: per-head transforms -> g, ptw, hpw
// grid = 256 m-tiles x 4 heads; 64 pv rows per block; weights staged in 32-col quarters.
__global__ __launch_bounds__(256) void k2_head(
    const float* __restrict__ pv_f32,
    const unsigned short* __restrict__ wp2cT_hi, const unsigned short* __restrict__ wp2cT_lo,
    const unsigned short* __restrict__ whpT_hi, const unsigned short* __restrict__ whpT_lo,
    const float* __restrict__ b_p2c, const float* __restrict__ bh_p,
    const float* __restrict__ Wa_c, const float* __restrict__ Wa_p,
    const float* __restrict__ uh, const float* __restrict__ p_mask,
    float* __restrict__ g_out, float* __restrict__ ptw_out, float* __restrict__ hpw_out)
{
  __shared__ __align__(16) short Ah[64*136], Al[64*136];   // pv tile hi/lo
  __shared__ __align__(16) short Wh_[32*136], Wl_[32*136]; // weight quarter hi/lo
  __shared__ float biasA[128], waA[128], biasB[128], waB[128], uh_l[128];
  int t = threadIdx.x;
  int h = blockIdx.x & 3, mt = blockIdx.x >> 2;
  int row0 = mt * 64;

  { // stage pv tile, split hi/lo
    int r = t >> 2, c0 = (t & 3) * 32;
    const float* src = pv_f32 + (row0 + r)*128 + c0;
    #pragma unroll
    for (int j = 0; j < 32; j += 4) {
      float4 v = *(const float4*)(src + j);
      uint2 hi, lo; split4(v, hi, lo);
      *(uint2*)&Ah[r*136 + c0 + j] = hi;
      *(uint2*)&Al[r*136 + c0 + j] = lo;
    }
  }
  if (t < 128) {
    biasA[t] = b_p2c[h*128 + t];
    waA[t]   = Wa_c[h*256 + 128 + t];   // Wa_c[:,128:] (c_trans term)
    biasB[t] = bh_p[h*128 + t];
    waB[t]   = Wa_p[h*256 + t];         // Wa_p[:,:128] (hp term)
    uh_l[t]  = uh[h*128 + t];
  }

  int w = t >> 6, lane = t & 63;
  int l15 = lane & 15, l4 = lane >> 4, kk = l4 * 8;
  int we = t >> 3, wk = (t & 7) * 16;   // weight staging: 32 e-rows x 128 k

  #pragma unroll
  for (int path = 0; path < 2; ++path) {
    const unsigned short* Wgh = path ? whpT_hi : wp2cT_hi;
    const unsigned short* Wgl = path ? whpT_lo : wp2cT_lo;
    const float* bias = path ? biasB : biasA;
    const float* wa   = path ? waB   : waA;
    float part[4] = {0.f, 0.f, 0.f, 0.f};
    #pragma unroll
    for (int q = 0; q < 4; ++q) {
      __syncthreads();
      { // stage weight quarter (cols q*32..q*32+31)
        const u16x8* sh = (const u16x8*)(Wgh + (h*128 + q*32 + we)*128 + wk);
        const u16x8* sl = (const u16x8*)(Wgl + (h*128 + q*32 + we)*128 + wk);
        u16x8 h0 = sh[0], h1 = sh[1], l0 = sl[0], l1 = sl[1];
        *(u16x8*)&Wh_[we*136 + wk]     = h0;
        *(u16x8*)&Wh_[we*136 + wk + 8] = h1;
        *(u16x8*)&Wl_[we*136 + wk]     = l0;
        *(u16x8*)&Wl_[we*136 + wk + 8] = l1;
      }
      __syncthreads();
      #pragma unroll
      for (int n = 0; n < 2; ++n) {
        f32x4 acc = (f32x4){0.f,0.f,0.f,0.f};
        #pragma unroll
        for (int kt = 0; kt < 4; ++kt) {
          bf16x8 ah = *(const bf16x8*)&Ah[(w*16 + l15)*136 + kt*32 + kk];
          bf16x8 al = *(const bf16x8*)&Al[(w*16 + l15)*136 + kt*32 + kk];
          bf16x8 bh = *(const bf16x8*)&Wh_[(n*16 + l15)*136 + kt*32 + kk];
          bf16x8 bl = *(const bf16x8*)&Wl_[(n*16 + l15)*136 + kt*32 + kk];
          acc = __builtin_amdgcn_mfma_f32_16x16x32_bf16(ah, bh, acc, 0, 0, 0);
          acc = __builtin_amdgcn_mfma_f32_16x16x32_bf16(ah, bl, acc, 0, 0, 0);
          acc = __builtin_amdgcn_mfma_f32_16x16x32_bf16(al, bh, acc, 0, 0, 0);
        }
        int col = q*32 + n*16 + l15;
        float bb = bias[col], ww = wa[col];
        #pragma unroll
        for (int r = 0; r < 4; ++r) part[r] += ww * tanh_fast(acc[r] + bb);
      }
    }
    #pragma unroll
    for (int off = 1; off < 16; off <<= 1) {
      #pragma unroll
      for (int r = 0; r < 4; ++r) part[r] += __shfl_xor(part[r], off, 64);
    }
    if (l15 == 0) {
      float* outp = path ? hpw_out : ptw_out;
      #pragma unroll
      for (int r = 0; r < 4; ++r) {
        int grow = row0 + w*16 + l4*4 + r;
        int bb = grow >> 10, m = grow & 1023;
        float v = part[r];
        if (!path) v *= p_mask[bb*1024 + m];  // fold p_mask into ptw
        outp[(bb*4 + h)*1024 + m] = v;
      }
    }
  }

  { // g = pv_f32 . uh (fp32)
    float u0 = uh_l[lane*2], u1 = uh_l[lane*2 + 1];
    for (int rr = 0; rr < 16; ++rr) {
      int grow = row0 + w*16 + rr;
      float2 v = *(const float2*)(pv_f32 + grow*128 + lane*2);
      float s = v.x*u0 + v.y*u1;
      #pragma unroll
      for (int off = 1; off < 64; off <<= 1) s += __shfl_xor(s, off, 64);
      if (lane == 0) {
        int bb = grow >> 10, m = grow & 1023;
        g_out[(bb*4 + h)*1024 + m] = s;
      }
    }
  }
}

// ---------------------------------------------------------------- K4: S1/S2 tanh reductions -> scores
__global__ __launch_bounds__(256) void k4_scores(
    const float* __restrict__ c, const float* __restrict__ c_mask, const float* __restrict__ p_mask,
    const float* __restrict__ g_arr, const float* __restrict__ ptw, const float* __restrict__ hpw,
    const float* __restrict__ hcw, const float* __restrict__ ctw,
    const float* __restrict__ ba_c, const float* __restrict__ ba_p,
    float* __restrict__ score_c, float* __restrict__ score_p)
{
  __shared__ float Av[1024], Bv[1024];
  int bid = blockIdx.x, t = threadIdx.x;
  bool sideP = bid >= 256;
  int i = bid & 255;
  int b = i >> 4, h = (i >> 2) & 3, ch = i & 3;
  int bh = b*4 + h;
  if (!sideP) {
    for (int j = t; j < 1024; j += 256) { Av[j] = g_arr[bh*1024 + j]; Bv[j] = ptw[bh*1024 + j]; }
    __syncthreads();
    int l = ch*256 + t;
    float cl = c[b*1024 + l];
    float a2 = 2.0f * cl;
    float acc = 0.f;
    #pragma unroll 8
    for (int m = 0; m < 1024; ++m) {
      float e  = __expf(a2 * Av[m]);
      float tt = 1.0f - __fdividef(2.0f, e + 1.0f);
      acc += Bv[m] * tt;
    }
    score_c[bh*1024 + l] = hcw[bh*1024 + l] + c_mask[b*1024 + l]*acc + ba_c[h];
  } else {
    for (int j = t; j < 1024; j += 256) { Av[j] = 2.0f*c[b*1024 + j]; Bv[j] = ctw[bh*1024 + j]; }
    __syncthreads();
    int m = ch*256 + t;
    float gm = g_arr[bh*1024 + m];
    float acc = 0.f;
    #pragma unroll 8
    for (int l = 0; l < 1024; ++l) {
      float e  = __expf(Av[l] * gm);
      float tt = 1.0f - __fdividef(2.0f, e + 1.0f);
      acc += Bv[l] * tt;
    }
    score_p[bh*1024 + m] = hpw[bh*1024 + m] + p_mask[b*1024 + m]*acc + ba_p[h];
  }
}

// ---------------------------------------------------------------- K5: masked softmax + pools
__device__ __forceinline__ float blk_red_max(float v, float* red, int t){
  red[t] = v; __syncthreads();
  for (int s = 128; s; s >>= 1) { if (t < s) red[t] = fmaxf(red[t], red[t+s]); __syncthreads(); }
  float r = red[0]; __syncthreads();
  return r;
}
__device__ __forceinline__ float blk_red_sum(float v, float* red, int t){
  red[t] = v; __syncthreads();
  for (int s = 128; s; s >>= 1) { if (t < s) red[t] += red[t+s]; __syncthreads(); }
  float r = red[0]; __syncthreads();
  return r;
}

__global__ __launch_bounds__(256) void k5_soft(
    const float* __restrict__ c, const float* __restrict__ c_mask, const float* __restrict__ p_mask,
    const float* __restrict__ score_c, const float* __restrict__ score_p,
    const float* __restrict__ pv_f32,
    float* __restrict__ s_c, float* __restrict__ pf_pool)
{
  __shared__ float sv[1024];
  __shared__ float red[256];
  int bid = blockIdx.x, t = threadIdx.x;
  bool sideP = bid >= 64;
  int i = bid & 63;
  int b = i >> 2, h = i & 3, bh = b*4 + h;
  const float* sc = (sideP ? score_p : score_c) + bh*1024;
  const float* mk = (sideP ? p_mask : c_mask) + b*1024;

  float v[4];
  float mx = -1e30f;
  #pragma unroll
  for (int j = 0; j < 4; ++j) { v[j] = sc[t + j*256]; mx = fmaxf(mx, v[j]); }
  mx = blk_red_max(mx, red, t);
  float sum = 0.f;
  #pragma unroll
  for (int j = 0; j < 4; ++j) {
    float e = __expf(v[j] - mx) * mk[t + j*256];
    sv[t + j*256] = e;
    sum += e;
  }
  sum = blk_red_sum(sum, red, t);
  float rinv = __fdividef(1.0f, sum + 1e-6f);

  if (!sideP) {
    float a = 0.f;
    #pragma unroll
    for (int j = 0; j < 4; ++j) a += sv[t + j*256] * rinv * c[b*1024 + t + j*256];
    a = blk_red_sum(a, red, t);
    if (t == 0) s_c[bh] = a;
  } else {
    #pragma unroll
    for (int j = 0; j < 4; ++j) sv[t + j*256] *= rinv;
    __syncthreads();
    int e = t & 127, half = t >> 7;
    float acc = 0.f;
    const float* base = pv_f32 + (b*1024 + half*512)*128 + e;
    #pragma unroll 4
    for (int m = 0; m < 512; ++m) acc += sv[half*512 + m] * base[m*128];
    red[t] = acc; __syncthreads();
    if (t < 128) pf_pool[bh*128 + t] = red[t] + red[t + 128];
  }
}

// ---------------------------------------------------------------- K6: finals + outer product
__global__ __launch_bounds__(256) void k6_final(
    const float* __restrict__ s_c, const float* __restrict__ wccv,
    const float* __restrict__ b_comb_c, const float* __restrict__ pf_pool,
    const float* __restrict__ W_comb_p, const float* __restrict__ b_comb_p,
    float* __restrict__ out)
{
  __shared__ float pfr[512];
  __shared__ float cfl[128], pfl[128];
  int b = blockIdx.x, t = threadIdx.x;
  pfr[t]       = pf_pool[b*512 + t];
  pfr[t + 256] = pf_pool[b*512 + t + 256];
  __syncthreads();
  if (t < 128) {
    float cf = b_comb_c[t];
    #pragma unroll
    for (int h = 0; h < 4; ++h) cf += s_c[b*4 + h] * wccv[h*128 + t];
    float pf = b_comb_p[t];
    #pragma unroll 8
    for (int i = 0; i < 512; ++i) pf += pfr[i] * W_comb_p[i*128 + t];
    cfl[t] = cf; pfl[t] = pf;
  }
  __syncthreads();
  #pragma unroll
  for (int k = 0; k < 64; ++k) {
    int idx = k*256 + t;
    out[b*16384 + idx] = cfl[idx >> 7] * pfl[idx & 127];
  }
}

// ---------------------------------------------------------------- launcher
extern "C" void kernel_launch(void* const* d_in, const int* in_sizes, int n_in,
                              void* d_out, int out_size, void* d_ws, size_t ws_size,
                              hipStream_t stream)
{
  const float* c        = (const float*)d_in[0];
  const float* c_mask   = (const float*)d_in[1];
  const float* p        = (const float*)d_in[2];
  const float* p_mask   = (const float*)d_in[3];
  const float* c_param  = (const float*)d_in[4];
  const float* p_param  = (const float*)d_in[5];
  const float* U        = (const float*)d_in[6];
  const float* W_p2c    = (const float*)d_in[7];
  const float* b_p2c    = (const float*)d_in[8];
  const float* W_c2p    = (const float*)d_in[9];
  const float* b_c2p    = (const float*)d_in[10];
  const float* Wh_c     = (const float*)d_in[11];
  const float* bh_c     = (const float*)d_in[12];
  const float* Wh_p     = (const float*)d_in[13];
  const float* bh_p     = (const float*)d_in[14];
  const float* Wa_c     = (const float*)d_in[15];
  const float* ba_c     = (const float*)d_in[16];
  const float* Wa_p     = (const float*)d_in[17];
  const float* ba_p     = (const float*)d_in[18];
  const float* W_comb_c = (const float*)d_in[19];
  const float* b_comb_c = (const float*)d_in[20];
  const float* W_comb_p = (const float*)d_in[21];
  const float* b_comb_p = (const float*)d_in[22];
  float* out = (float*)d_out;

  char* ws = (char*)d_ws;
  float*          pv_f32   = (float*)         (ws + 0);
  unsigned short* ppT_hi   = (unsigned short*)(ws + 8388608);
  unsigned short* ppT_lo   = (unsigned short*)(ws + 8650752);
  unsigned short* wp2cT_hi = (unsigned short*)(ws + 8912896);
  unsigned short* wp2cT_lo = (unsigned short*)(ws + 9043968);
  unsigned short* whpT_hi  = (unsigned short*)(ws + 9175040);
  unsigned short* whpT_lo  = (unsigned short*)(ws + 9306112);
  float*          uh       = (float*)         (ws + 9437184);
  float*          wccv     = (float*)         (ws + 9439232);
  float*          g_arr    = (float*)         (ws + 9441280);
  float*          ptw      = (float*)         (ws + 9703424);
  float*          hpw      = (float*)         (ws + 9965568);
  float*          hcw      = (float*)         (ws + 10227712);
  float*          ctw      = (float*)         (ws + 10489856);
  float*          score_c  = (float*)         (ws + 10752000);
  float*          score_p  = (float*)         (ws + 11014144);
  float*          s_c      = (float*)         (ws + 11276288);
  float*          pf_pool  = (float*)         (ws + 11276544);

  k0_prep<<<dim3(292), dim3(256), 0, stream>>>(
      c, c_mask, c_param, p_param, U, W_p2c, W_c2p, Wh_c, Wh_p,
      bh_c, b_c2p, Wa_c, Wa_p, W_comb_c,
      ppT_hi, ppT_lo, wp2cT_hi, wp2cT_lo, whpT_hi, whpT_lo,
      uh, wccv, hcw, ctw);

  k1_pv<<<dim3(512), dim3(256), 0, stream>>>(p, ppT_hi, ppT_lo, pv_f32);

  k2_head<<<dim3(1024), dim3(256), 0, stream>>>(
      pv_f32, wp2cT_hi, wp2cT_lo, whpT_hi, whpT_lo,
      b_p2c, bh_p, Wa_c, Wa_p, uh, p_mask,
      g_arr, ptw, hpw);

  k4_scores<<<dim3(512), dim3(256), 0, stream>>>(
      c, c_mask, p_mask, g_arr, ptw, hpw, hcw, ctw, ba_c, ba_p,
      score_c, score_p);

  k5_soft<<<dim3(128), dim3(256), 0, stream>>>(
      c, c_mask, p_mask, score_c, score_p, pv_f32, s_c, pf_pool);

  k6_final<<<dim3(16), dim3(256), 0, stream>>>(
      s_c, wccv, b_comb_c, pf_pool, W_comb_p, b_comb_p, out);
}

// Round 3
// 194.624 us; speedup vs baseline: 1.1271x; 1.1271x over previous
//
#include <hip/hip_runtime.h>

// BIATT: B=16, Lc=Lp=1024, D=128, H=4, PFEAT=1024. All inputs fp32.
// Algebra: cv is rank-1 (c[b,l]*cp[d]) => A = tanh(c[b,l]*g[b,h,m]);
// scores reduce to 1D sums over tanh of an outer product.
// Precision: split-bf16 (hi+lo) MFMA => ~fp32-equivalent GEMMs.
// K4: sum B*tanh = sumB - 2*sum B/(1+e^{2x}); pairs read via scalar loads.

using bf16x8 = __attribute__((ext_vector_type(8))) short;
using u16x8  = __attribute__((ext_vector_type(8))) unsigned short;
using f32x4  = __attribute__((ext_vector_type(4))) float;

#define TWO_LOG2E 2.8853900817779268f

__device__ __forceinline__ float tanh_fast(float x){
  float e = __expf(2.0f * x);
  return 1.0f - __fdividef(2.0f, e + 1.0f);
}
__device__ __forceinline__ unsigned short f2bf(float f){
  unsigned u = __float_as_uint(f);
  u = (u + 0x7FFFu + ((u >> 16) & 1u)) >> 16; // RNE
  return (unsigned short)u;
}
__device__ __forceinline__ float bf2f(unsigned short s){
  return __uint_as_float((unsigned)s << 16);
}
__device__ __forceinline__ void split4(float4 v, uint2& hi, uint2& lo){
  unsigned short hx = f2bf(v.x), hy = f2bf(v.y), hz = f2bf(v.z), hw = f2bf(v.w);
  unsigned short lx = f2bf(v.x - bf2f(hx)), ly = f2bf(v.y - bf2f(hy));
  unsigned short lz = f2bf(v.z - bf2f(hz)), lw = f2bf(v.w - bf2f(hw));
  hi = make_uint2((unsigned)hx | ((unsigned)hy << 16), (unsigned)hz | ((unsigned)hw << 16));
  lo = make_uint2((unsigned)lx | ((unsigned)ly << 16), (unsigned)lz | ((unsigned)lw << 16));
}

// ---------------------------------------------------------------- K0: prep
__global__ __launch_bounds__(256) void k0_prep(
    const float* __restrict__ c, const float* __restrict__ c_mask,
    const float* __restrict__ c_param, const float* __restrict__ p_param,
    const float* __restrict__ U, const float* __restrict__ W_p2c,
    const float* __restrict__ W_c2p, const float* __restrict__ Wh_c,
    const float* __restrict__ Wh_p, const float* __restrict__ bh_c,
    const float* __restrict__ b_c2p, const float* __restrict__ Wa_c,
    const float* __restrict__ Wa_p, const float* __restrict__ W_comb_c,
    const float* __restrict__ ba_c,
    unsigned short* __restrict__ ppT_hi, unsigned short* __restrict__ ppT_lo,
    unsigned short* __restrict__ wp2cT_hi, unsigned short* __restrict__ wp2cT_lo,
    unsigned short* __restrict__ whpT_hi, unsigned short* __restrict__ whpT_lo,
    float* __restrict__ uh, float* __restrict__ wccv,
    float* __restrict__ score_c, float2* __restrict__ pairP)
{
  int bid = blockIdx.x, t = threadIdx.x;
  if (bid < 4) {
    int h = bid;
    if (t < 128) {
      float s_uh = 0.f, s_wcc = 0.f;
      for (int d = 0; d < 128; ++d) {
        float cp = c_param[d];
        s_uh  += cp * U[(h*128 + d)*128 + t];
        s_wcc += cp * W_comb_c[(h*128 + d)*128 + t];
      }
      uh[h*128 + t]   = s_uh;
      wccv[h*128 + t] = s_wcc;
    }
  } else if (bid < 36) {
    int base = (bid - 4) * 8192;
    for (int j = 0; j < 32; ++j) {
      int idx = base + j*256 + t;
      float v; unsigned short* dh; unsigned short* dl; int o;
      if (idx < 131072) {                       // ppT[e][k] = p_param[k][e]
        int e = idx >> 10, k = idx & 1023;
        v = p_param[k*128 + e]; dh = ppT_hi; dl = ppT_lo; o = idx;
      } else if (idx < 196608) {                // wp2cT[h][e][k] = W_p2c[h][k][e]
        int i2 = idx - 131072;
        int k = i2 & 127, e = (i2 >> 7) & 127, h = i2 >> 14;
        v = W_p2c[(h*128 + k)*128 + e]; dh = wp2cT_hi; dl = wp2cT_lo; o = i2;
      } else {                                  // whpT[h][e][k] = Wh_p[h][k][e]
        int i2 = idx - 196608;
        int k = i2 & 127, e = (i2 >> 7) & 127, h = i2 >> 14;
        v = Wh_p[(h*128 + k)*128 + e]; dh = whpT_hi; dl = whpT_lo; o = i2;
      }
      unsigned short hh = f2bf(v);
      dh[o] = hh;
      dl[o] = f2bf(v - bf2f(hh));
    }
  } else {
    int i = bid - 36;
    int b = i >> 4, h = (i >> 2) & 3, lc = i & 3;
    __shared__ float whc_l[128], wc2p_l[128], bhc_l[128], bc2p_l[128], wac1_l[128], wap2_l[128];
    if (t < 128) {
      float s1 = 0.f, s2 = 0.f;
      for (int d = 0; d < 128; ++d) {
        float cp = c_param[d];
        s1 += cp * Wh_c[(h*128 + d)*128 + t];
        s2 += cp * W_c2p[(h*128 + d)*128 + t];
      }
      whc_l[t] = s1; wc2p_l[t] = s2;
      bhc_l[t]  = bh_c[h*128 + t];
      bc2p_l[t] = b_c2p[h*128 + t];
      wac1_l[t] = Wa_c[h*256 + t];
      wap2_l[t] = Wa_p[h*256 + 128 + t];
    }
    __syncthreads();
    int l = lc*256 + t;
    float cl = c[b*1024 + l];
    float a1 = 0.f, a2 = 0.f;
    for (int e = 0; e < 128; ++e) {
      a1 += wac1_l[e] * tanh_fast(cl*whc_l[e]  + bhc_l[e]);
      a2 += wap2_l[e] * tanh_fast(cl*wc2p_l[e] + bc2p_l[e]);
    }
    int o = (b*4 + h)*1024 + l;
    score_c[o] = a1 + ba_c[h];                     // base: hcw + ba_c
    pairP[o] = make_float2(TWO_LOG2E * cl, c_mask[b*1024 + l] * a2); // (kappa, ctw)
  }
}

// ---------------------------------------------------------------- K1: pv = p @ p_param (split-bf16 MFMA)
__global__ __launch_bounds__(256) void k1_pv(
    const float* __restrict__ p,
    const unsigned short* __restrict__ ppT_hi, const unsigned short* __restrict__ ppT_lo,
    float* __restrict__ pv_f32)
{
  __shared__ __align__(16) short Ah[32*40], Al[32*40];   // [row][k], pitch 40
  __shared__ __align__(16) short Bh[128*40], Bl[128*40]; // [col][k], pitch 40
  int t = threadIdx.x;
  int row0 = blockIdx.x * 32;

  int arow = t >> 3, ak = (t & 7) * 4;
  int bcol = t >> 1, bk = (t & 1) * 16;
  const float* pA = p + (row0 + arow)*1024 + ak;
  const unsigned short* pBh = ppT_hi + bcol*1024 + bk;
  const unsigned short* pBl = ppT_lo + bcol*1024 + bk;

  float4 ra  = *(const float4*)(pA);
  u16x8  rbh0 = *(const u16x8*)(pBh), rbh1 = *(const u16x8*)(pBh + 8);
  u16x8  rbl0 = *(const u16x8*)(pBl), rbl1 = *(const u16x8*)(pBl + 8);

  f32x4 acc[4];
  #pragma unroll
  for (int n = 0; n < 4; ++n) acc[n] = (f32x4){0.f,0.f,0.f,0.f};

  int w = t >> 6, lane = t & 63;
  int l15 = lane & 15, kk = (lane >> 4) * 8;
  int rowblk = (w & 1) * 16, colblk = (w >> 1) * 64;
  int arow_l = rowblk + l15;

  for (int kt = 0; kt < 32; ++kt) {
    __syncthreads();
    {
      uint2 hi, lo; split4(ra, hi, lo);
      *(uint2*)&Ah[arow*40 + ak] = hi;
      *(uint2*)&Al[arow*40 + ak] = lo;
      *(u16x8*)&Bh[bcol*40 + bk]     = rbh0;
      *(u16x8*)&Bh[bcol*40 + bk + 8] = rbh1;
      *(u16x8*)&Bl[bcol*40 + bk]     = rbl0;
      *(u16x8*)&Bl[bcol*40 + bk + 8] = rbl1;
    }
    if (kt < 31) {
      ra   = *(const float4*)(pA + (kt+1)*32);
      rbh0 = *(const u16x8*)(pBh + (kt+1)*32);
      rbh1 = *(const u16x8*)(pBh + (kt+1)*32 + 8);
      rbl0 = *(const u16x8*)(pBl + (kt+1)*32);
      rbl1 = *(const u16x8*)(pBl + (kt+1)*32 + 8);
    }
    __syncthreads();
    bf16x8 afh = *(const bf16x8*)&Ah[arow_l*40 + kk];
    bf16x8 afl = *(const bf16x8*)&Al[arow_l*40 + kk];
    #pragma unroll
    for (int n = 0; n < 4; ++n) {
      bf16x8 bfh = *(const bf16x8*)&Bh[(colblk + n*16 + l15)*40 + kk];
      bf16x8 bfl = *(const bf16x8*)&Bl[(colblk + n*16 + l15)*40 + kk];
      acc[n] = __builtin_amdgcn_mfma_f32_16x16x32_bf16(afh, bfh, acc[n], 0, 0, 0);
      acc[n] = __builtin_amdgcn_mfma_f32_16x16x32_bf16(afh, bfl, acc[n], 0, 0, 0);
      acc[n] = __builtin_amdgcn_mfma_f32_16x16x32_bf16(afl, bfh, acc[n], 0, 0, 0);
    }
  }
  #pragma unroll
  for (int n = 0; n < 4; ++n) {
    int col = colblk + n*16 + l15;
    #pragma unroll
    for (int r = 0; r < 4; ++r) {
      int row = row0 + rowblk + (lane >> 4)*4 + r;
      pv_f32[row*128 + col] = acc[n][r];
    }
  }
}

// ---------------------------------------------------------------- K2: per-head transforms -> g/pairC, score_p base
__global__ __launch_bounds__(256) void k2_head(
    const float* __restrict__ pv_f32,
    const unsigned short* __restrict__ wp2cT_hi, const unsigned short* __restrict__ wp2cT_lo,
    const unsigned short* __restrict__ whpT_hi, const unsigned short* __restrict__ whpT_lo,
    const float* __restrict__ b_p2c, const float* __restrict__ bh_p,
    const float* __restrict__ Wa_c, const float* __restrict__ Wa_p,
    const float* __restrict__ uh, const float* __restrict__ p_mask,
    const float* __restrict__ ba_p,
    float* __restrict__ g_out, float2* __restrict__ pairC, float* __restrict__ score_p)
{
  __shared__ __align__(16) short Ah[64*136], Al[64*136];   // pv tile hi/lo
  __shared__ __align__(16) short Wh_[32*136], Wl_[32*136]; // weight quarter hi/lo
  __shared__ float biasA[128], waA[128], biasB[128], waB[128], uh_l[128];
  int t = threadIdx.x;
  int h = blockIdx.x & 3, mt = blockIdx.x >> 2;
  int row0 = mt * 64;

  { // stage pv tile, split hi/lo
    int r = t >> 2, c0 = (t & 3) * 32;
    const float* src = pv_f32 + (row0 + r)*128 + c0;
    #pragma unroll
    for (int j = 0; j < 32; j += 4) {
      float4 v = *(const float4*)(src + j);
      uint2 hi, lo; split4(v, hi, lo);
      *(uint2*)&Ah[r*136 + c0 + j] = hi;
      *(uint2*)&Al[r*136 + c0 + j] = lo;
    }
  }
  if (t < 128) {
    biasA[t] = b_p2c[h*128 + t];
    waA[t]   = Wa_c[h*256 + 128 + t];   // Wa_c[:,128:] (c_trans term)
    biasB[t] = bh_p[h*128 + t];
    waB[t]   = Wa_p[h*256 + t];         // Wa_p[:,:128] (hp term)
    uh_l[t]  = uh[h*128 + t];
  }

  int w = t >> 6, lane = t & 63;
  int l15 = lane & 15, l4 = lane >> 4, kk = l4 * 8;
  int we = t >> 3, wk = (t & 7) * 16;

  #pragma unroll
  for (int path = 0; path < 2; ++path) {
    const unsigned short* Wgh = path ? whpT_hi : wp2cT_hi;
    const unsigned short* Wgl = path ? whpT_lo : wp2cT_lo;
    const float* bias = path ? biasB : biasA;
    const float* wa   = path ? waB   : waA;
    float part[4] = {0.f, 0.f, 0.f, 0.f};
    #pragma unroll
    for (int q = 0; q < 4; ++q) {
      __syncthreads();
      { // stage weight quarter (cols q*32..q*32+31)
        const u16x8* sh = (const u16x8*)(Wgh + (h*128 + q*32 + we)*128 + wk);
        const u16x8* sl = (const u16x8*)(Wgl + (h*128 + q*32 + we)*128 + wk);
        u16x8 h0 = sh[0], h1 = sh[1], l0 = sl[0], l1 = sl[1];
        *(u16x8*)&Wh_[we*136 + wk]     = h0;
        *(u16x8*)&Wh_[we*136 + wk + 8] = h1;
        *(u16x8*)&Wl_[we*136 + wk]     = l0;
        *(u16x8*)&Wl_[we*136 + wk + 8] = l1;
      }
      __syncthreads();
      #pragma unroll
      for (int n = 0; n < 2; ++n) {
        f32x4 acc = (f32x4){0.f,0.f,0.f,0.f};
        #pragma unroll
        for (int kt = 0; kt < 4; ++kt) {
          bf16x8 ah = *(const bf16x8*)&Ah[(w*16 + l15)*136 + kt*32 + kk];
          bf16x8 al = *(const bf16x8*)&Al[(w*16 + l15)*136 + kt*32 + kk];
          bf16x8 bh = *(const bf16x8*)&Wh_[(n*16 + l15)*136 + kt*32 + kk];
          bf16x8 bl = *(const bf16x8*)&Wl_[(n*16 + l15)*136 + kt*32 + kk];
          acc = __builtin_amdgcn_mfma_f32_16x16x32_bf16(ah, bh, acc, 0, 0, 0);
          acc = __builtin_amdgcn_mfma_f32_16x16x32_bf16(ah, bl, acc, 0, 0, 0);
          acc = __builtin_amdgcn_mfma_f32_16x16x32_bf16(al, bh, acc, 0, 0, 0);
        }
        int col = q*32 + n*16 + l15;
        float bb = bias[col], ww = wa[col];
        #pragma unroll
        for (int r = 0; r < 4; ++r) part[r] += ww * tanh_fast(acc[r] + bb);
      }
    }
    #pragma unroll
    for (int off = 1; off < 16; off <<= 1) {
      #pragma unroll
      for (int r = 0; r < 4; ++r) part[r] += __shfl_xor(part[r], off, 64);
    }
    if (l15 == 0) {
      #pragma unroll
      for (int r = 0; r < 4; ++r) {
        int grow = row0 + w*16 + l4*4 + r;
        int bb = grow >> 10, m = grow & 1023;
        int idx = (bb*4 + h)*1024 + m;
        if (!path) pairC[idx].y = p_mask[bb*1024 + m] * part[r];   // ptw (mask folded)
        else       score_p[idx] = part[r] + ba_p[h];               // base: hpw + ba_p
      }
    }
  }

  { // g = pv_f32 . uh (fp32)
    float u0 = uh_l[lane*2], u1 = uh_l[lane*2 + 1];
    for (int rr = 0; rr < 16; ++rr) {
      int grow = row0 + w*16 + rr;
      float2 v = *(const float2*)(pv_f32 + grow*128 + lane*2);
      float s = v.x*u0 + v.y*u1;
      #pragma unroll
      for (int off = 1; off < 64; off <<= 1) s += __shfl_xor(s, off, 64);
      if (lane == 0) {
        int bb = grow >> 10, m = grow & 1023;
        int idx = (bb*4 + h)*1024 + m;
        g_out[idx] = s;
        pairC[idx].x = TWO_LOG2E * s;   // kappa for c-side
      }
    }
  }
}

// ---------------------------------------------------------------- K4: tanh outer-product reductions
// grid 2048 = side(2) x b(16) x h(4) x alpha-chunk(4) x j-chunk(4); 256 thr.
// partial = mask * (sumB_chunk - 2 * sum_j B_j / (1 + e^{alpha*kappa_j})) -> atomicAdd
__global__ __launch_bounds__(256) void k4_scores(
    const float* __restrict__ c, const float* __restrict__ c_mask, const float* __restrict__ p_mask,
    const float* __restrict__ g_arr,
    const float2* __restrict__ pairC, const float2* __restrict__ pairP,
    float* __restrict__ score_c, float* __restrict__ score_p)
{
  __shared__ float red[256];
  int bid = blockIdx.x, t = threadIdx.x;
  int side = bid >> 10;
  int r = bid & 1023;
  int b = r >> 6, h = (r >> 4) & 3, ac = (r >> 2) & 3, jc = r & 3;
  int bh = b*4 + h;
  const float2* pair = (side ? pairP : pairC) + bh*1024 + jc*256;
  int ai = ac*256 + t;
  float alpha = side ? g_arr[bh*1024 + ai] : c[b*1024 + ai];
  float mask  = side ? p_mask[b*1024 + ai] : c_mask[b*1024 + ai];

  red[t] = pair[t].y; __syncthreads();
  for (int s = 128; s; s >>= 1) { if (t < s) red[t] += red[t+s]; __syncthreads(); }
  float sB = red[0];

  float acc = 0.f;
  #pragma unroll 8
  for (int j = 0; j < 256; ++j) {
    float2 gb = pair[j];                      // block-uniform -> scalar loads
    float e  = exp2f(alpha * gb.x);           // e^{2*alpha*g}
    float rc = __builtin_amdgcn_rcpf(e + 1.0f);
    acc = fmaf(gb.y, rc, acc);
  }
  float part = mask * (sB - 2.0f*acc);
  atomicAdd((side ? score_p : score_c) + bh*1024 + ai, part);
}

// ---------------------------------------------------------------- K5: masked softmax + pools
__device__ __forceinline__ float blk_red_max(float v, float* red, int t){
  red[t] = v; __syncthreads();
  for (int s = 128; s; s >>= 1) { if (t < s) red[t] = fmaxf(red[t], red[t+s]); __syncthreads(); }
  float r = red[0]; __syncthreads();
  return r;
}
__device__ __forceinline__ float blk_red_sum(float v, float* red, int t){
  red[t] = v; __syncthreads();
  for (int s = 128; s; s >>= 1) { if (t < s) red[t] += red[t+s]; __syncthreads(); }
  float r = red[0]; __syncthreads();
  return r;
}

__global__ __launch_bounds__(256) void k5_soft(
    const float* __restrict__ c, const float* __restrict__ c_mask, const float* __restrict__ p_mask,
    const float* __restrict__ score_c, const float* __restrict__ score_p,
    const float* __restrict__ pv_f32,
    float* __restrict__ s_c, float* __restrict__ pf_pool)
{
  __shared__ float sv[1024];
  __shared__ float red[256];
  int bid = blockIdx.x, t = threadIdx.x;
  bool sideP = bid >= 64;
  int i = bid & 63;
  int b = i >> 2, h = i & 3, bh = b*4 + h;
  const float* sc = (sideP ? score_p : score_c) + bh*1024;
  const float* mk = (sideP ? p_mask : c_mask) + b*1024;

  float v[4];
  float mx = -1e30f;
  #pragma unroll
  for (int j = 0; j < 4; ++j) { v[j] = sc[t + j*256]; mx = fmaxf(mx, v[j]); }
  mx = blk_red_max(mx, red, t);
  float sum = 0.f;
  #pragma unroll
  for (int j = 0; j < 4; ++j) {
    float e = __expf(v[j] - mx) * mk[t + j*256];
    sv[t + j*256] = e;
    sum += e;
  }
  sum = blk_red_sum(sum, red, t);
  float rinv = __fdividef(1.0f, sum + 1e-6f);

  if (!sideP) {
    float a = 0.f;
    #pragma unroll
    for (int j = 0; j < 4; ++j) a += sv[t + j*256] * rinv * c[b*1024 + t + j*256];
    a = blk_red_sum(a, red, t);
    if (t == 0) s_c[bh] = a;
  } else {
    #pragma unroll
    for (int j = 0; j < 4; ++j) sv[t + j*256] *= rinv;
    __syncthreads();
    int e = t & 127, half = t >> 7;
    float acc = 0.f;
    const float* base = pv_f32 + (b*1024 + half*512)*128 + e;
    #pragma unroll 4
    for (int m = 0; m < 512; ++m) acc += sv[half*512 + m] * base[m*128];
    red[t] = acc; __syncthreads();
    if (t < 128) pf_pool[bh*128 + t] = red[t] + red[t + 128];
  }
}

// ---------------------------------------------------------------- K6: finals + outer product
__global__ __launch_bounds__(256) void k6_final(
    const float* __restrict__ s_c, const float* __restrict__ wccv,
    const float* __restrict__ b_comb_c, const float* __restrict__ pf_pool,
    const float* __restrict__ W_comb_p, const float* __restrict__ b_comb_p,
    float* __restrict__ out)
{
  __shared__ float pfr[512];
  __shared__ float cfl[128], pfl[128];
  int b = blockIdx.x, t = threadIdx.x;
  pfr[t]       = pf_pool[b*512 + t];
  pfr[t + 256] = pf_pool[b*512 + t + 256];
  __syncthreads();
  if (t < 128) {
    float cf = b_comb_c[t];
    #pragma unroll
    for (int h = 0; h < 4; ++h) cf += s_c[b*4 + h] * wccv[h*128 + t];
    float pf = b_comb_p[t];
    #pragma unroll 8
    for (int i = 0; i < 512; ++i) pf += pfr[i] * W_comb_p[i*128 + t];
    cfl[t] = cf; pfl[t] = pf;
  }
  __syncthreads();
  #pragma unroll
  for (int k = 0; k < 64; ++k) {
    int idx = k*256 + t;
    out[b*16384 + idx] = cfl[idx >> 7] * pfl[idx & 127];
  }
}

// ---------------------------------------------------------------- launcher
extern "C" void kernel_launch(void* const* d_in, const int* in_sizes, int n_in,
                              void* d_out, int out_size, void* d_ws, size_t ws_size,
                              hipStream_t stream)
{
  const float* c        = (const float*)d_in[0];
  const float* c_mask   = (const float*)d_in[1];
  const float* p        = (const float*)d_in[2];
  const float* p_mask   = (const float*)d_in[3];
  const float* c_param  = (const float*)d_in[4];
  const float* p_param  = (const float*)d_in[5];
  const float* U        = (const float*)d_in[6];
  const float* W_p2c    = (const float*)d_in[7];
  const float* b_p2c    = (const float*)d_in[8];
  const float* W_c2p    = (const float*)d_in[9];
  const float* b_c2p    = (const float*)d_in[10];
  const float* Wh_c     = (const float*)d_in[11];
  const float* bh_c     = (const float*)d_in[12];
  const float* Wh_p     = (const float*)d_in[13];
  const float* bh_p     = (const float*)d_in[14];
  const float* Wa_c     = (const float*)d_in[15];
  const float* ba_c     = (const float*)d_in[16];
  const float* Wa_p     = (const float*)d_in[17];
  const float* ba_p     = (const float*)d_in[18];
  const float* W_comb_c = (const float*)d_in[19];
  const float* b_comb_c = (const float*)d_in[20];
  const float* W_comb_p = (const float*)d_in[21];
  const float* b_comb_p = (const float*)d_in[22];
  float* out = (float*)d_out;

  char* ws = (char*)d_ws;
  float*          pv_f32   = (float*)         (ws + 0);
  unsigned short* ppT_hi   = (unsigned short*)(ws + 8388608);
  unsigned short* ppT_lo   = (unsigned short*)(ws + 8650752);
  unsigned short* wp2cT_hi = (unsigned short*)(ws + 8912896);
  unsigned short* wp2cT_lo = (unsigned short*)(ws + 9043968);
  unsigned short* whpT_hi  = (unsigned short*)(ws + 9175040);
  unsigned short* whpT_lo  = (unsigned short*)(ws + 9306112);
  float*          uh       = (float*)         (ws + 9437184);
  float*          wccv     = (float*)         (ws + 9439232);
  float*          g_arr    = (float*)         (ws + 9441280);
  float2*         pairC    = (float2*)        (ws + 9703424);
  float2*         pairP    = (float2*)        (ws + 10227712);
  float*          score_c  = (float*)         (ws + 10752000);
  float*          score_p  = (float*)         (ws + 11014144);
  float*          s_c      = (float*)         (ws + 11276288);
  float*          pf_pool  = (float*)         (ws + 11276544);

  k0_prep<<<dim3(292), dim3(256), 0, stream>>>(
      c, c_mask, c_param, p_param, U, W_p2c, W_c2p, Wh_c, Wh_p,
      bh_c, b_c2p, Wa_c, Wa_p, W_comb_c, ba_c,
      ppT_hi, ppT_lo, wp2cT_hi, wp2cT_lo, whpT_hi, whpT_lo,
      uh, wccv, score_c, pairP);

  k1_pv<<<dim3(512), dim3(256), 0, stream>>>(p, ppT_hi, ppT_lo, pv_f32);

  k2_head<<<dim3(1024), dim3(256), 0, stream>>>(
      pv_f32, wp2cT_hi, wp2cT_lo, whpT_hi, whpT_lo,
      b_p2c, bh_p, Wa_c, Wa_p, uh, p_mask, ba_p,
      g_arr, pairC, score_p);

  k4_scores<<<dim3(2048), dim3(256), 0, stream>>>(
      c, c_mask, p_mask, g_arr, pairC, pairP, score_c, score_p);

  k5_soft<<<dim3(128), dim3(256), 0, stream>>>(
      c, c_mask, p_mask, score_c, score_p, pv_f32, s_c, pf_pool);

  k6_final<<<dim3(16), dim3(256), 0, stream>>>(
      s_c, wccv, b_comb_c, pf_pool, W_comb_p, b_comb_p, out);
}

// Round 4
// 168.394 us; speedup vs baseline: 1.3027x; 1.1558x over previous
//
#include <hip/hip_runtime.h>

// BIATT: B=16, Lc=Lp=1024, D=128, H=4, PFEAT=1024. All inputs fp32.
// Algebra: cv is rank-1 (c[b,l]*cp[d]) => A = tanh(c[b,l]*g[b,h,m]);
// scores reduce to 1D sums over tanh of an outer product.
// Precision: split-bf16 (hi+lo) MFMA => ~fp32-equivalent GEMMs.
// K4: sum B*tanh = sumB - 2*sum B/(1+e^{2x}); raw v_exp_f32 (exp2f is libm-slow).

using bf16x8 = __attribute__((ext_vector_type(8))) short;
using u16x8  = __attribute__((ext_vector_type(8))) unsigned short;
using f32x4  = __attribute__((ext_vector_type(4))) float;

#define TWO_LOG2E 2.8853900817779268f

__device__ __forceinline__ float exp2_raw(float x){
#if __has_builtin(__builtin_amdgcn_exp2f)
  return __builtin_amdgcn_exp2f(x);
#else
  float r; asm("v_exp_f32 %0, %1" : "=v"(r) : "v"(x)); return r;
#endif
}
__device__ __forceinline__ float tanh_fast(float x){
  float e = exp2_raw(x * TWO_LOG2E);
  return fmaf(-2.0f, __builtin_amdgcn_rcpf(e + 1.0f), 1.0f);
}
__device__ __forceinline__ unsigned short f2bf(float f){
  unsigned u = __float_as_uint(f);
  u = (u + 0x7FFFu + ((u >> 16) & 1u)) >> 16; // RNE
  return (unsigned short)u;
}
__device__ __forceinline__ float bf2f(unsigned short s){
  return __uint_as_float((unsigned)s << 16);
}
__device__ __forceinline__ void split4(float4 v, uint2& hi, uint2& lo){
  unsigned short hx = f2bf(v.x), hy = f2bf(v.y), hz = f2bf(v.z), hw = f2bf(v.w);
  unsigned short lx = f2bf(v.x - bf2f(hx)), ly = f2bf(v.y - bf2f(hy));
  unsigned short lz = f2bf(v.z - bf2f(hz)), lw = f2bf(v.w - bf2f(hw));
  hi = make_uint2((unsigned)hx | ((unsigned)hy << 16), (unsigned)hz | ((unsigned)hw << 16));
  lo = make_uint2((unsigned)lx | ((unsigned)ly << 16), (unsigned)lz | ((unsigned)lw << 16));
}
__device__ __forceinline__ unsigned cvt_pk_bf16(float a, float b){
  unsigned r;
  asm("v_cvt_pk_bf16_f32 %0, %1, %2" : "=v"(r) : "v"(a), "v"(b));
  return r;
}
// split 8 f32 -> hi/lo bf16x8 fragments (lo = x - hi is exact in f32)
__device__ __forceinline__ void split8(const float4& x, const float4& y, bf16x8& hi, bf16x8& lo){
  unsigned h0 = cvt_pk_bf16(x.x, x.y);
  unsigned h1 = cvt_pk_bf16(x.z, x.w);
  unsigned h2 = cvt_pk_bf16(y.x, y.y);
  unsigned h3 = cvt_pk_bf16(y.z, y.w);
  float r0 = x.x - __uint_as_float(h0 << 16);
  float r1 = x.y - __uint_as_float(h0 & 0xffff0000u);
  float r2 = x.z - __uint_as_float(h1 << 16);
  float r3 = x.w - __uint_as_float(h1 & 0xffff0000u);
  float r4 = y.x - __uint_as_float(h2 << 16);
  float r5 = y.y - __uint_as_float(h2 & 0xffff0000u);
  float r6 = y.z - __uint_as_float(h3 << 16);
  float r7 = y.w - __uint_as_float(h3 & 0xffff0000u);
  uint4 H = make_uint4(h0, h1, h2, h3);
  uint4 L = make_uint4(cvt_pk_bf16(r0, r1), cvt_pk_bf16(r2, r3),
                       cvt_pk_bf16(r4, r5), cvt_pk_bf16(r6, r7));
  hi = __builtin_bit_cast(bf16x8, H);
  lo = __builtin_bit_cast(bf16x8, L);
}

// ---------------------------------------------------------------- K0: prep
__global__ __launch_bounds__(256) void k0_prep(
    const float* __restrict__ c, const float* __restrict__ c_mask,
    const float* __restrict__ c_param, const float* __restrict__ p_param,
    const float* __restrict__ U, const float* __restrict__ W_p2c,
    const float* __restrict__ W_c2p, const float* __restrict__ Wh_c,
    const float* __restrict__ Wh_p, const float* __restrict__ bh_c,
    const float* __restrict__ b_c2p, const float* __restrict__ Wa_c,
    const float* __restrict__ Wa_p, const float* __restrict__ W_comb_c,
    const float* __restrict__ ba_c,
    unsigned short* __restrict__ ppT_hi, unsigned short* __restrict__ ppT_lo,
    unsigned short* __restrict__ wp2cT_hi, unsigned short* __restrict__ wp2cT_lo,
    unsigned short* __restrict__ whpT_hi, unsigned short* __restrict__ whpT_lo,
    float* __restrict__ uh, float* __restrict__ wccv,
    float* __restrict__ score_c, float2* __restrict__ pairP)
{
  int bid = blockIdx.x, t = threadIdx.x;
  if (bid < 4) {
    int h = bid;
    if (t < 128) {
      float s_uh = 0.f, s_wcc = 0.f;
      for (int d = 0; d < 128; ++d) {
        float cp = c_param[d];
        s_uh  += cp * U[(h*128 + d)*128 + t];
        s_wcc += cp * W_comb_c[(h*128 + d)*128 + t];
      }
      uh[h*128 + t]   = s_uh;
      wccv[h*128 + t] = s_wcc;
    }
  } else if (bid < 36) {
    int base = (bid - 4) * 8192;
    for (int j = 0; j < 32; ++j) {
      int idx = base + j*256 + t;
      float v; unsigned short* dh; unsigned short* dl; int o;
      if (idx < 131072) {                       // ppT[e][k] = p_param[k][e]
        int e = idx >> 10, k = idx & 1023;
        v = p_param[k*128 + e]; dh = ppT_hi; dl = ppT_lo; o = idx;
      } else if (idx < 196608) {                // wp2cT[h][e][k] = W_p2c[h][k][e]
        int i2 = idx - 131072;
        int k = i2 & 127, e = (i2 >> 7) & 127, h = i2 >> 14;
        v = W_p2c[(h*128 + k)*128 + e]; dh = wp2cT_hi; dl = wp2cT_lo; o = i2;
      } else {                                  // whpT[h][e][k] = Wh_p[h][k][e]
        int i2 = idx - 196608;
        int k = i2 & 127, e = (i2 >> 7) & 127, h = i2 >> 14;
        v = Wh_p[(h*128 + k)*128 + e]; dh = whpT_hi; dl = whpT_lo; o = i2;
      }
      unsigned short hh = f2bf(v);
      dh[o] = hh;
      dl[o] = f2bf(v - bf2f(hh));
    }
  } else {
    int i = bid - 36;
    int b = i >> 4, h = (i >> 2) & 3, lc = i & 3;
    __shared__ float whc_l[128], wc2p_l[128], bhc_l[128], bc2p_l[128], wac1_l[128], wap2_l[128];
    if (t < 128) {
      float s1 = 0.f, s2 = 0.f;
      for (int d = 0; d < 128; ++d) {
        float cp = c_param[d];
        s1 += cp * Wh_c[(h*128 + d)*128 + t];
        s2 += cp * W_c2p[(h*128 + d)*128 + t];
      }
      whc_l[t] = s1; wc2p_l[t] = s2;
      bhc_l[t]  = bh_c[h*128 + t];
      bc2p_l[t] = b_c2p[h*128 + t];
      wac1_l[t] = Wa_c[h*256 + t];
      wap2_l[t] = Wa_p[h*256 + 128 + t];
    }
    __syncthreads();
    int l = lc*256 + t;
    float cl = c[b*1024 + l];
    float a1 = 0.f, a2 = 0.f;
    for (int e = 0; e < 128; ++e) {
      a1 += wac1_l[e] * tanh_fast(cl*whc_l[e]  + bhc_l[e]);
      a2 += wap2_l[e] * tanh_fast(cl*wc2p_l[e] + bc2p_l[e]);
    }
    int o = (b*4 + h)*1024 + l;
    score_c[o] = a1 + ba_c[h];                     // base: hcw + ba_c
    pairP[o] = make_float2(TWO_LOG2E * cl, c_mask[b*1024 + l] * a2); // (kappa, ctw)
  }
}

// ---------------------------------------------------------------- K1: pv = p @ p_param (split-bf16 MFMA)
// BM=64 (4 waves x 16 rows), BN=128, BK=64, 16 chunks. A: global->reg direct
// in frag order + in-reg split; B: LDS pitch-72 (2-way banks, free).
__global__ __launch_bounds__(256) void k1_pv(
    const float* __restrict__ p,
    const unsigned short* __restrict__ ppT_hi, const unsigned short* __restrict__ ppT_lo,
    float* __restrict__ pv_f32)
{
  __shared__ __align__(16) short Bh[128*72];
  __shared__ __align__(16) short Bl[128*72];
  int t = threadIdx.x;
  int row0 = blockIdx.x * 64;
  int w = t >> 6, lane = t & 63;
  int l15 = lane & 15, l4 = lane >> 4;

  int bcol = t >> 1, bkh = (t & 1) * 32;
  const unsigned short* gBh = ppT_hi + bcol*1024 + bkh;
  const unsigned short* gBl = ppT_lo + bcol*1024 + bkh;
  short* sBh = &Bh[bcol*72 + bkh];
  short* sBl = &Bl[bcol*72 + bkh];

  const float* gA = p + (row0 + w*16 + l15)*1024 + l4*8;

  u16x8 rb[8];        // hi[0..3], lo[4..7]
  float4 ra[4];       // (ks,half): [2*ks+half]

  #pragma unroll
  for (int j = 0; j < 4; ++j) {
    rb[j]   = *(const u16x8*)(gBh + j*8);
    rb[4+j] = *(const u16x8*)(gBl + j*8);
  }
  #pragma unroll
  for (int j = 0; j < 4; ++j)
    ra[j] = *(const float4*)(gA + (j>>1)*32 + (j&1)*4);

  f32x4 acc[8];
  #pragma unroll
  for (int n = 0; n < 8; ++n) acc[n] = (f32x4){0.f,0.f,0.f,0.f};

  for (int c = 0; c < 16; ++c) {
    __syncthreads();
    #pragma unroll
    for (int j = 0; j < 4; ++j) {
      *(u16x8*)(sBh + j*8) = rb[j];
      *(u16x8*)(sBl + j*8) = rb[4+j];
    }
    if (c < 15) {
      #pragma unroll
      for (int j = 0; j < 4; ++j) {
        rb[j]   = *(const u16x8*)(gBh + (c+1)*64 + j*8);
        rb[4+j] = *(const u16x8*)(gBl + (c+1)*64 + j*8);
      }
    }
    float4 ran0, ran1, ran2, ran3;
    if (c < 15) {
      const float* gAn = gA + (c+1)*64;
      ran0 = *(const float4*)(gAn);
      ran1 = *(const float4*)(gAn + 4);
      ran2 = *(const float4*)(gAn + 32);
      ran3 = *(const float4*)(gAn + 36);
    }
    __syncthreads();
    #pragma unroll
    for (int ks = 0; ks < 2; ++ks) {
      bf16x8 ah, al;
      split8(ra[2*ks], ra[2*ks+1], ah, al);
      #pragma unroll
      for (int ct = 0; ct < 8; ++ct) {
        bf16x8 bh = *(const bf16x8*)&Bh[(ct*16 + l15)*72 + ks*32 + l4*8];
        bf16x8 bl = *(const bf16x8*)&Bl[(ct*16 + l15)*72 + ks*32 + l4*8];
        acc[ct] = __builtin_amdgcn_mfma_f32_16x16x32_bf16(ah, bh, acc[ct], 0, 0, 0);
        acc[ct] = __builtin_amdgcn_mfma_f32_16x16x32_bf16(ah, bl, acc[ct], 0, 0, 0);
        acc[ct] = __builtin_amdgcn_mfma_f32_16x16x32_bf16(al, bh, acc[ct], 0, 0, 0);
      }
    }
    if (c < 15) { ra[0] = ran0; ra[1] = ran1; ra[2] = ran2; ra[3] = ran3; }
  }

  #pragma unroll
  for (int ct = 0; ct < 8; ++ct) {
    int col = ct*16 + l15;
    #pragma unroll
    for (int r = 0; r < 4; ++r) {
      int row = row0 + w*16 + l4*4 + r;
      pv_f32[row*128 + col] = acc[ct][r];
    }
  }
}

// ---------------------------------------------------------------- K2: per-head transforms -> g/pairC, score_p base
__global__ __launch_bounds__(256) void k2_head(
    const float* __restrict__ pv_f32,
    const unsigned short* __restrict__ wp2cT_hi, const unsigned short* __restrict__ wp2cT_lo,
    const unsigned short* __restrict__ whpT_hi, const unsigned short* __restrict__ whpT_lo,
    const float* __restrict__ b_p2c, const float* __restrict__ bh_p,
    const float* __restrict__ Wa_c, const float* __restrict__ Wa_p,
    const float* __restrict__ uh, const float* __restrict__ p_mask,
    const float* __restrict__ ba_p,
    float* __restrict__ g_out, float2* __restrict__ pairC, float* __restrict__ score_p)
{
  __shared__ __align__(16) short Ah[64*136], Al[64*136];   // pv tile hi/lo
  __shared__ __align__(16) short Wh_[32*136], Wl_[32*136]; // weight quarter hi/lo
  __shared__ float biasA[128], waA[128], biasB[128], waB[128], uh_l[128];
  int t = threadIdx.x;
  int h = blockIdx.x & 3, mt = blockIdx.x >> 2;
  int row0 = mt * 64;

  { // stage pv tile, split hi/lo
    int r = t >> 2, c0 = (t & 3) * 32;
    const float* src = pv_f32 + (row0 + r)*128 + c0;
    #pragma unroll
    for (int j = 0; j < 32; j += 4) {
      float4 v = *(const float4*)(src + j);
      uint2 hi, lo; split4(v, hi, lo);
      *(uint2*)&Ah[r*136 + c0 + j] = hi;
      *(uint2*)&Al[r*136 + c0 + j] = lo;
    }
  }
  if (t < 128) {
    biasA[t] = b_p2c[h*128 + t];
    waA[t]   = Wa_c[h*256 + 128 + t];   // Wa_c[:,128:] (c_trans term)
    biasB[t] = bh_p[h*128 + t];
    waB[t]   = Wa_p[h*256 + t];         // Wa_p[:,:128] (hp term)
    uh_l[t]  = uh[h*128 + t];
  }

  int w = t >> 6, lane = t & 63;
  int l15 = lane & 15, l4 = lane >> 4, kk = l4 * 8;
  int we = t >> 3, wk = (t & 7) * 16;

  #pragma unroll
  for (int path = 0; path < 2; ++path) {
    const unsigned short* Wgh = path ? whpT_hi : wp2cT_hi;
    const unsigned short* Wgl = path ? whpT_lo : wp2cT_lo;
    const float* bias = path ? biasB : biasA;
    const float* wa   = path ? waB   : waA;
    float part[4] = {0.f, 0.f, 0.f, 0.f};
    #pragma unroll
    for (int q = 0; q < 4; ++q) {
      __syncthreads();
      { // stage weight quarter (cols q*32..q*32+31)
        const u16x8* sh = (const u16x8*)(Wgh + (h*128 + q*32 + we)*128 + wk);
        const u16x8* sl = (const u16x8*)(Wgl + (h*128 + q*32 + we)*128 + wk);
        u16x8 h0 = sh[0], h1 = sh[1], l0 = sl[0], l1 = sl[1];
        *(u16x8*)&Wh_[we*136 + wk]     = h0;
        *(u16x8*)&Wh_[we*136 + wk + 8] = h1;
        *(u16x8*)&Wl_[we*136 + wk]     = l0;
        *(u16x8*)&Wl_[we*136 + wk + 8] = l1;
      }
      __syncthreads();
      #pragma unroll
      for (int n = 0; n < 2; ++n) {
        f32x4 acc = (f32x4){0.f,0.f,0.f,0.f};
        #pragma unroll
        for (int kt = 0; kt < 4; ++kt) {
          bf16x8 ah = *(const bf16x8*)&Ah[(w*16 + l15)*136 + kt*32 + kk];
          bf16x8 al = *(const bf16x8*)&Al[(w*16 + l15)*136 + kt*32 + kk];
          bf16x8 bh = *(const bf16x8*)&Wh_[(n*16 + l15)*136 + kt*32 + kk];
          bf16x8 bl = *(const bf16x8*)&Wl_[(n*16 + l15)*136 + kt*32 + kk];
          acc = __builtin_amdgcn_mfma_f32_16x16x32_bf16(ah, bh, acc, 0, 0, 0);
          acc = __builtin_amdgcn_mfma_f32_16x16x32_bf16(ah, bl, acc, 0, 0, 0);
          acc = __builtin_amdgcn_mfma_f32_16x16x32_bf16(al, bh, acc, 0, 0, 0);
        }
        int col = q*32 + n*16 + l15;
        float bb = bias[col], ww = wa[col];
        #pragma unroll
        for (int r = 0; r < 4; ++r) part[r] += ww * tanh_fast(acc[r] + bb);
      }
    }
    #pragma unroll
    for (int off = 1; off < 16; off <<= 1) {
      #pragma unroll
      for (int r = 0; r < 4; ++r) part[r] += __shfl_xor(part[r], off, 64);
    }
    if (l15 == 0) {
      #pragma unroll
      for (int r = 0; r < 4; ++r) {
        int grow = row0 + w*16 + l4*4 + r;
        int bb = grow >> 10, m = grow & 1023;
        int idx = (bb*4 + h)*1024 + m;
        if (!path) pairC[idx].y = p_mask[bb*1024 + m] * part[r];   // ptw (mask folded)
        else       score_p[idx] = part[r] + ba_p[h];               // base: hpw + ba_p
      }
    }
  }

  { // g = pv_f32 . uh (fp32)
    float u0 = uh_l[lane*2], u1 = uh_l[lane*2 + 1];
    for (int rr = 0; rr < 16; ++rr) {
      int grow = row0 + w*16 + rr;
      float2 v = *(const float2*)(pv_f32 + grow*128 + lane*2);
      float s = v.x*u0 + v.y*u1;
      #pragma unroll
      for (int off = 1; off < 64; off <<= 1) s += __shfl_xor(s, off, 64);
      if (lane == 0) {
        int bb = grow >> 10, m = grow & 1023;
        int idx = (bb*4 + h)*1024 + m;
        g_out[idx] = s;
        pairC[idx].x = TWO_LOG2E * s;   // kappa for c-side
      }
    }
  }
}

// ---------------------------------------------------------------- K4: tanh outer-product reductions
// grid 2048 = side(2) x b(16) x h(4) x alpha-chunk(4) x j-chunk(4); 256 thr.
__global__ __launch_bounds__(256) void k4_scores(
    const float* __restrict__ c, const float* __restrict__ c_mask, const float* __restrict__ p_mask,
    const float* __restrict__ g_arr,
    const float2* __restrict__ pairC, const float2* __restrict__ pairP,
    float* __restrict__ score_c, float* __restrict__ score_p)
{
  __shared__ float red[256];
  int bid = blockIdx.x, t = threadIdx.x;
  int side = bid >> 10;
  int r = bid & 1023;
  int b = r >> 6, h = (r >> 4) & 3, ac = (r >> 2) & 3, jc = r & 3;
  int bh = b*4 + h;
  const float2* pair = (side ? pairP : pairC) + bh*1024 + jc*256;
  int ai = ac*256 + t;
  float alpha = side ? g_arr[bh*1024 + ai] : c[b*1024 + ai];
  float mask  = side ? p_mask[b*1024 + ai] : c_mask[b*1024 + ai];

  red[t] = pair[t].y; __syncthreads();
  for (int s = 128; s; s >>= 1) { if (t < s) red[t] += red[t+s]; __syncthreads(); }
  float sB = red[0];

  float acc = 0.f;
  #pragma unroll 16
  for (int j = 0; j < 256; ++j) {
    float2 gb = pair[j];                      // block-uniform -> scalar loads
    float e = exp2_raw(alpha * gb.x);         // e^{2*alpha*g}, raw v_exp_f32
    acc = fmaf(gb.y, __builtin_amdgcn_rcpf(e + 1.0f), acc);
  }
  float part = mask * (sB - 2.0f*acc);
  atomicAdd((side ? score_p : score_c) + bh*1024 + ai, part);
}

// ---------------------------------------------------------------- K5: masked softmax + pools
__device__ __forceinline__ float blk_red_max(float v, float* red, int t){
  red[t] = v; __syncthreads();
  for (int s = 128; s; s >>= 1) { if (t < s) red[t] = fmaxf(red[t], red[t+s]); __syncthreads(); }
  float r = red[0]; __syncthreads();
  return r;
}
__device__ __forceinline__ float blk_red_sum(float v, float* red, int t){
  red[t] = v; __syncthreads();
  for (int s = 128; s; s >>= 1) { if (t < s) red[t] += red[t+s]; __syncthreads(); }
  float r = red[0]; __syncthreads();
  return r;
}

__global__ __launch_bounds__(256) void k5_soft(
    const float* __restrict__ c, const float* __restrict__ c_mask, const float* __restrict__ p_mask,
    const float* __restrict__ score_c, const float* __restrict__ score_p,
    const float* __restrict__ pv_f32,
    float* __restrict__ s_c, float* __restrict__ pf_pool)
{
  __shared__ float sv[1024];
  __shared__ float red[256];
  int bid = blockIdx.x, t = threadIdx.x;
  bool sideP = bid >= 64;
  int i = bid & 63;
  int b = i >> 2, h = i & 3, bh = b*4 + h;
  const float* sc = (sideP ? score_p : score_c) + bh*1024;
  const float* mk = (sideP ? p_mask : c_mask) + b*1024;

  float v[4];
  float mx = -1e30f;
  #pragma unroll
  for (int j = 0; j < 4; ++j) { v[j] = sc[t + j*256]; mx = fmaxf(mx, v[j]); }
  mx = blk_red_max(mx, red, t);
  float sum = 0.f;
  #pragma unroll
  for (int j = 0; j < 4; ++j) {
    float e = exp2_raw((v[j] - mx) * 1.4426950408889634f) * mk[t + j*256];
    sv[t + j*256] = e;
    sum += e;
  }
  sum = blk_red_sum(sum, red, t);
  float rinv = __fdividef(1.0f, sum + 1e-6f);

  if (!sideP) {
    float a = 0.f;
    #pragma unroll
    for (int j = 0; j < 4; ++j) a += sv[t + j*256] * rinv * c[b*1024 + t + j*256];
    a = blk_red_sum(a, red, t);
    if (t == 0) s_c[bh] = a;
  } else {
    #pragma unroll
    for (int j = 0; j < 4; ++j) sv[t + j*256] *= rinv;
    __syncthreads();
    int e = t & 127, half = t >> 7;
    float acc = 0.f;
    const float* base = pv_f32 + (b*1024 + half*512)*128 + e;
    #pragma unroll 4
    for (int m = 0; m < 512; ++m) acc += sv[half*512 + m] * base[m*128];
    red[t] = acc; __syncthreads();
    if (t < 128) pf_pool[bh*128 + t] = red[t] + red[t + 128];
  }
}

// ---------------------------------------------------------------- K6: finals + outer product
__global__ __launch_bounds__(256) void k6_final(
    const float* __restrict__ s_c, const float* __restrict__ wccv,
    const float* __restrict__ b_comb_c, const float* __restrict__ pf_pool,
    const float* __restrict__ W_comb_p, const float* __restrict__ b_comb_p,
    float* __restrict__ out)
{
  __shared__ float pfr[512];
  __shared__ float cfl[128], pfl[128];
  int b = blockIdx.x, t = threadIdx.x;
  pfr[t]       = pf_pool[b*512 + t];
  pfr[t + 256] = pf_pool[b*512 + t + 256];
  __syncthreads();
  if (t < 128) {
    float cf = b_comb_c[t];
    #pragma unroll
    for (int h = 0; h < 4; ++h) cf += s_c[b*4 + h] * wccv[h*128 + t];
    float pf = b_comb_p[t];
    #pragma unroll 8
    for (int i = 0; i < 512; ++i) pf += pfr[i] * W_comb_p[i*128 + t];
    cfl[t] = cf; pfl[t] = pf;
  }
  __syncthreads();
  #pragma unroll
  for (int k = 0; k < 64; ++k) {
    int idx = k*256 + t;
    out[b*16384 + idx] = cfl[idx >> 7] * pfl[idx & 127];
  }
}

// ---------------------------------------------------------------- launcher
extern "C" void kernel_launch(void* const* d_in, const int* in_sizes, int n_in,
                              void* d_out, int out_size, void* d_ws, size_t ws_size,
                              hipStream_t stream)
{
  const float* c        = (const float*)d_in[0];
  const float* c_mask   = (const float*)d_in[1];
  const float* p        = (const float*)d_in[2];
  const float* p_mask   = (const float*)d_in[3];
  const float* c_param  = (const float*)d_in[4];
  const float* p_param  = (const float*)d_in[5];
  const float* U        = (const float*)d_in[6];
  const float* W_p2c    = (const float*)d_in[7];
  const float* b_p2c    = (const float*)d_in[8];
  const float* W_c2p    = (const float*)d_in[9];
  const float* b_c2p    = (const float*)d_in[10];
  const float* Wh_c     = (const float*)d_in[11];
  const float* bh_c     = (const float*)d_in[12];
  const float* Wh_p     = (const float*)d_in[13];
  const float* bh_p     = (const float*)d_in[14];
  const float* Wa_c     = (const float*)d_in[15];
  const float* ba_c     = (const float*)d_in[16];
  const float* Wa_p     = (const float*)d_in[17];
  const float* ba_p     = (const float*)d_in[18];
  const float* W_comb_c = (const float*)d_in[19];
  const float* b_comb_c = (const float*)d_in[20];
  const float* W_comb_p = (const float*)d_in[21];
  const float* b_comb_p = (const float*)d_in[22];
  float* out = (float*)d_out;

  char* ws = (char*)d_ws;
  float*          pv_f32   = (float*)         (ws + 0);
  unsigned short* ppT_hi   = (unsigned short*)(ws + 8388608);
  unsigned short* ppT_lo   = (unsigned short*)(ws + 8650752);
  unsigned short* wp2cT_hi = (unsigned short*)(ws + 8912896);
  unsigned short* wp2cT_lo = (unsigned short*)(ws + 9043968);
  unsigned short* whpT_hi  = (unsigned short*)(ws + 9175040);
  unsigned short* whpT_lo  = (unsigned short*)(ws + 9306112);
  float*          uh       = (float*)         (ws + 9437184);
  float*          wccv     = (float*)         (ws + 9439232);
  float*          g_arr    = (float*)         (ws + 9441280);
  float2*         pairC    = (float2*)        (ws + 9703424);
  float2*         pairP    = (float2*)        (ws + 10227712);
  float*          score_c  = (float*)         (ws + 10752000);
  float*          score_p  = (float*)         (ws + 11014144);
  float*          s_c      = (float*)         (ws + 11276288);
  float*          pf_pool  = (float*)         (ws + 11276544);

  k0_prep<<<dim3(292), dim3(256), 0, stream>>>(
      c, c_mask, c_param, p_param, U, W_p2c, W_c2p, Wh_c, Wh_p,
      bh_c, b_c2p, Wa_c, Wa_p, W_comb_c, ba_c,
      ppT_hi, ppT_lo, wp2cT_hi, wp2cT_lo, whpT_hi, whpT_lo,
      uh, wccv, score_c, pairP);

  k1_pv<<<dim3(256), dim3(256), 0, stream>>>(p, ppT_hi, ppT_lo, pv_f32);

  k2_head<<<dim3(1024), dim3(256), 0, stream>>>(
      pv_f32, wp2cT_hi, wp2cT_lo, whpT_hi, whpT_lo,
      b_p2c, bh_p, Wa_c, Wa_p, uh, p_mask, ba_p,
      g_arr, pairC, score_p);

  k4_scores<<<dim3(2048), dim3(256), 0, stream>>>(
      c, c_mask, p_mask, g_arr, pairC, pairP, score_c, score_p);

  k5_soft<<<dim3(128), dim3(256), 0, stream>>>(
      c, c_mask, p_mask, score_c, score_p, pv_f32, s_c, pf_pool);

  k6_final<<<dim3(16), dim3(256), 0, stream>>>(
      s_c, wccv, b_comb_c, pf_pool, W_comb_p, b_comb_p, out);
}